// Round 2
// baseline (1429.067 us; speedup 1.0000x reference)
//
#include <hip/hip_runtime.h>
#include <hip/hip_bf16.h>

// MyRnn: h_t = tanh(emb[idx_t] @ W_xh + b_h + h_{t-1} @ W_hh), 80 steps,
// out = sigmoid(h_80 @ W_out + b_out).
//
// R4: FULLY-STREAMED design. R2/R3 post-mortem: the "resident weights in
// VGPRs" plan needed ~160 weight VGPRs but the allocator pinned the kernel
// at 128 VGPRs and spilled ~137 regs to scratch (WRITE_SIZE=36MB spill
// stores, ~40MB/step scratch reloads -> 13MB/step L2 miss, 13us/step of
// reload latency, MfmaUtil 4%). Neither launch_bounds(512,1),
// amdgpu_waves_per_eu(2,2) nor volatile-asm pins changed VGPR_Count=128
// (pins can't forbid spilling; the allocator re-spilled around them).
//
// So: make 128 VGPRs SUFFICIENT. Nothing resident. All 20 ksteps (4 Wxh +
// 16 Whh) stream from L2 through a 4-deep register pipeline (sB[4][NT] =
// 64 VGPR; total live ~115 < 128 -> no spills by construction). Weight
// loads are t-invariant and h-independent, so the pipeline crosses the
// step barrier: iterations 16..19 of step t prefetch step t+1's X-frags.
// Prep kernel emits weights in MFMA-FRAGMENT ORDER [wave][ks][nt][lane][16B]
// so each streamed load is one contiguous 1KB wave transaction.
// Per block per step: 640KB from L2 (L2-resident: Wt 512K + Xt 128K per
// XCD). 16 blocks/XCD * 640KB / 4.3TB/s ~= 2.4us/step -> ~195us floor.

#define T_LEN   80
#define EMB_D   100
#define UNITS   512
#define ROWS    16
#define NBLK    128
#define NTHR    512
#define NT      4                // n-tiles (16 cols) per wave
#define KSH     16               // K-steps for W_hh (512/32)
#define KSX     4                // K-steps for W_xh (128/32, zero-padded)
#define KTOT    (KSH + KSX)      // 20 unified ksteps: 0..3 = x, 4..19 = h

typedef __bf16 bf16x8 __attribute__((ext_vector_type(8)));
typedef float  f32x4  __attribute__((ext_vector_type(4)));

__device__ __forceinline__ float fast_tanh(float x) {
    float e = __builtin_amdgcn_exp2f(x * 2.8853900817779268f);
    return 1.0f - 2.0f * __builtin_amdgcn_rcpf(1.0f + e);
}

// ---- prep: rewrite weights into MFMA-fragment order in d_ws ----
// FW[w][ks][nt][lane][8]: element j = Whh[ks*32 + (lane>>4)*8 + j][w*64 + nt*16 + (lane&15)]
// FX[w][ks][nt][lane][8]: same from Wxh, k >= 100 -> 0
// One thread per 8-elem fragment: 32768 W-frags + 8192 X-frags = 40960.
__global__ void prep_kernel(const float* __restrict__ Whh,
                            const float* __restrict__ Wxh,
                            __bf16* __restrict__ FW, __bf16* __restrict__ FX) {
    const int f = blockIdx.x * 256 + threadIdx.x;
    if (f < 32768) {
        const int lane = f & 63, nt = (f >> 6) & 3, ks = (f >> 8) & 15, w = f >> 12;
        const int c  = (w << 6) + (nt << 4) + (lane & 15);
        const int kb = (ks << 5) + ((lane >> 4) << 3);
        __bf16* d = FW + (size_t)f * 8;
        #pragma unroll
        for (int j = 0; j < 8; ++j)
            d[j] = (__bf16)Whh[(kb + j) * UNITS + c];
    } else {
        const int f2 = f - 32768;
        const int lane = f2 & 63, nt = (f2 >> 6) & 3, ks = (f2 >> 8) & 3, w = f2 >> 10;
        const int c  = (w << 6) + (nt << 4) + (lane & 15);
        const int kb = (ks << 5) + ((lane >> 4) << 3);
        __bf16* d = FX + (size_t)f2 * 8;
        #pragma unroll
        for (int j = 0; j < 8; ++j)
            d[j] = (kb + j < EMB_D) ? (__bf16)Wxh[(kb + j) * UNITS + c] : (__bf16)0.0f;
    }
}

__global__ __launch_bounds__(NTHR)
void rnn_kernel(const int*   __restrict__ inputs,   // [2048][80]
                const float* __restrict__ emb,      // [35000][100]
                const float* __restrict__ bh,       // [512]
                const float* __restrict__ Wout,     // [512]
                const float* __restrict__ bout,     // [1]
                const __bf16* __restrict__ FW,      // frag-order Whh (ws)
                const __bf16* __restrict__ FX,      // frag-order Wxh (ws)
                float*       __restrict__ out)      // [2048]
{
    // h: 16 rows x 512 bf16, 16B-chunk XOR swizzle:
    //   elem(m,k) = m*512 + (((k>>3) ^ (m&7))<<3) + (k&7)
    // x: 16 rows x 128 bf16, same swizzle, row stride 128.
    __shared__ alignas(16) __bf16 hbuf[2][16 * UNITS];
    __shared__ alignas(16) __bf16 xbuf[2][16 * 128];

    const int tid  = threadIdx.x;
    const int wave = tid >> 6;       // 0..7
    const int lane = tid & 63;
    const int q    = lane >> 4;      // MFMA quad
    const int ln   = lane & 15;
    const int e7   = ln & 7;
    const int qa   = q ^ (e7 & 3);
    const int kx   = e7 >> 2;
    const int r0   = blockIdx.x * ROWS;

    float bhv[NT];
    #pragma unroll
    for (int nt = 0; nt < NT; ++nt)
        bhv[nt] = bh[(wave << 6) + (nt << 4) + ln];

    // streamed B-frag pipeline, 4 slots x NT frags (64 VGPR)
    bf16x8 sB[4][NT];

    // prefetch kstep kk's 4 B-frags into dst[NT]; kk is compile-time const
    auto pf = [&](int kk, bf16x8* dst) {
        if (kk < KSX) {
            const __bf16* p = FX + ((wave << 13) + (kk << 11) + (lane << 3));
            #pragma unroll
            for (int nt = 0; nt < NT; ++nt)
                dst[nt] = *(const bf16x8*)(p + (nt << 9));
        } else {
            const int ks = kk - KSX;
            const __bf16* p = FW + ((wave << 15) + (ks << 11) + (lane << 3));
            #pragma unroll
            for (int nt = 0; nt < NT; ++nt)
                dst[nt] = *(const bf16x8*)(p + (nt << 9));
        }
    };

    // zero LDS (h0 = 0; x pad cols k>=100 stay 0 forever)
    {
        int4 z; z.x = z.y = z.z = z.w = 0;
        int4* hp = (int4*)&hbuf[0][0];
        #pragma unroll
        for (int i = 0; i < 4; ++i) hp[tid + i * NTHR] = z;   // 32KB
        int4* xp = (int4*)&xbuf[0][0];
        xp[tid] = z;                                          // 8KB
    }
    __syncthreads();

    // stage embedded x_t (bf16, swizzled); wave w does rows w and w+8
    auto stage = [&](int t, __bf16* xb) {
        #pragma unroll
        for (int rr = 0; rr < 2; ++rr) {
            const int r = wave + (rr << 3);
            const int idxv = inputs[(r0 + r) * T_LEN + t];
            const float* er = emb + (size_t)idxv * EMB_D;
            const int k0 = lane;          // < 100 always
            xb[(r << 7) + ((((k0 >> 3) ^ (r & 7)) << 3) | (k0 & 7))] = (__bf16)er[k0];
            const int k1 = lane + 64;
            if (k1 < EMB_D)
                xb[(r << 7) + ((((k1 >> 3) ^ (r & 7)) << 3) | (k1 & 7))] = (__bf16)er[k1];
        }
    };

    auto step = [&](const __bf16* hb_r, const __bf16* xb_r, __bf16* hb_w) {
        f32x4 acc[NT];
        #pragma unroll
        for (int nt = 0; nt < NT; ++nt) {
            f32x4 a = {bhv[nt], bhv[nt], bhv[nt], bhv[nt]};
            acc[nt] = a;
        }

        const int xbase = (ln << 7) + (qa << 3);
        const int hbase = (ln << 9) + (qa << 3);

        // unified 20-kstep loop: consume slot (kk&3), refill with kstep kk+4
        // (wraps to next step's X-frags for kk>=16 -> pipeline crosses barrier)
        #pragma unroll
        for (int kk = 0; kk < KTOT; ++kk) {
            bf16x8 a;
            if (kk < KSX)
                a = *(const bf16x8*)&xb_r[xbase + ((kk ^ kx) << 5)];
            else
                a = *(const bf16x8*)&hb_r[hbase + (((kk - KSX) ^ kx) << 5)];
            const int s = kk & 3;
            #pragma unroll
            for (int nt = 0; nt < NT; ++nt)
                acc[nt] = __builtin_amdgcn_mfma_f32_16x16x32_bf16(a, sB[s][nt], acc[nt], 0, 0, 0);
            pf((kk + 4) % KTOT, sB[s]);
        }

        // write h' : C/D layout col=ln, row=4q+i (all 16 rows real)
        #pragma unroll
        for (int nt = 0; nt < NT; ++nt) {
            const int cc = (wave << 3) + (nt << 1) + (ln >> 3);  // col>>3
            #pragma unroll
            for (int i = 0; i < 4; ++i) {
                const int row = (q << 2) + i;
                hb_w[(row << 9) + (((cc ^ (row & 7)) << 3) | (ln & 7))] =
                    (__bf16)fast_tanh(acc[nt][i]);
            }
        }
    };

    // pipeline prologue: slots 0..3 <- ksteps 0..3 (the X-frags)
    pf(0, sB[0]); pf(1, sB[1]); pf(2, sB[2]); pf(3, sB[3]);

    stage(0, xbuf[0]);
    __syncthreads();

    #pragma unroll 1
    for (int t = 0; t < T_LEN; t += 2) {
        stage(t + 1, xbuf[1]);                        // t+1 <= 79
        step(hbuf[0], xbuf[0], hbuf[1]);
        __syncthreads();
        if (t + 2 < T_LEN) stage(t + 2, xbuf[0]);
        step(hbuf[1], xbuf[1], hbuf[0]);
        __syncthreads();
    }
    // h_last in hbuf[0], rows 0..15

    // output head: wave w reduces rows w and w+8
    #pragma unroll
    for (int rr = 0; rr < 2; ++rr) {
        const int m = wave + (rr << 3);
        const bf16x8 hv = *(const bf16x8*)&hbuf[0][(m << 9) + ((lane ^ wave) << 3)];
        float s = 0.0f;
        #pragma unroll
        for (int j = 0; j < 8; ++j)
            s += (float)hv[j] * Wout[(lane << 3) + j];
        #pragma unroll
        for (int off = 32; off > 0; off >>= 1)
            s += __shfl_down(s, off, 64);
        if (lane == 0) {
            const float logit = s + bout[0];
            out[r0 + m] = __builtin_amdgcn_rcpf(
                1.0f + __builtin_amdgcn_exp2f(-logit * 1.4426950408889634f));
        }
    }
}

extern "C" void kernel_launch(void* const* d_in, const int* in_sizes, int n_in,
                              void* d_out, int out_size, void* d_ws, size_t ws_size,
                              hipStream_t stream) {
    __bf16* FW = (__bf16*)d_ws;                 // 512*512*2 = 512 KB (frag order)
    __bf16* FX = FW + UNITS * UNITS;            // 512*128*2 = 128 KB (frag order)
    prep_kernel<<<dim3(160), dim3(256), 0, stream>>>(
        (const float*)d_in[3],   // W_hh
        (const float*)d_in[2],   // W_xh
        FW, FX);
    rnn_kernel<<<dim3(NBLK), dim3(NTHR), 0, stream>>>(
        (const int*)d_in[0],     // inputs
        (const float*)d_in[1],   // emb_table
        (const float*)d_in[4],   // b_h
        (const float*)d_in[5],   // W_out
        (const float*)d_in[6],   // b_out
        FW, FX,
        (float*)d_out);
}